// Round 16
// baseline (122.327 us; speedup 1.0000x reference)
//
#include <hip/hip_runtime.h>
#include <stdint.h>

typedef float f32x4 __attribute__((ext_vector_type(4)));
typedef int   i32x4 __attribute__((ext_vector_type(4)));
typedef __bf16 bf16x8 __attribute__((ext_vector_type(8)));

#define NN 8192
#define DDIM 128

// ---- stash layout inside d_out (bytes) ----
// Row = 512B: 4 chunks x [h(32 cols)=64B | l(32 cols)=64B], 16B units
// XOR-swizzled WITHIN each 8-unit chunk by (row&7).
// A'(8192x512B) = C rows 0..127 ; B' = C rows 128..255
// norms n1[8192],n2[8192] f32 = last 64KB = C rows 8190..8191
#define APRIME_OFF 0u
#define BPRIME_OFF (8192u*512u)
#define NORM_OFF   (268435456u - 65536u)

__device__ __forceinline__ uint32_t pk2(__bf16 a, __bf16 b) {
    return (uint32_t)__builtin_bit_cast(unsigned short, a)
         | ((uint32_t)__builtin_bit_cast(unsigned short, b) << 16);
}

// ---------------- launch 1: prep — split each row ONCE (R13-R15 verbatim) ----------------
__global__ __launch_bounds__(256) void prep_kernel(
    const float* __restrict__ X1, const float* __restrict__ X2,
    const float* __restrict__ log_l, char* __restrict__ outbuf)
{
    int t = threadIdx.x, wave = t >> 6, lane = t & 63;
    int row = blockIdx.x * 4 + wave;          // 0..16383
    const float* X; uint32_t base; float* nrm;
    if (row < NN) {
        X = X1 + (size_t)row * DDIM;
        base = APRIME_OFF + (uint32_t)row * 512u;
        nrm = (float*)(outbuf + NORM_OFF) + row;
    } else {
        int r2 = row - NN;
        X = X2 + (size_t)r2 * DDIM;
        base = BPRIME_OFF + (uint32_t)r2 * 512u;
        nrm = (float*)(outbuf + NORM_OFF) + NN + r2;
    }
    int c0 = lane * 2;
    float2 x = *(const float2*)(X + c0);
    float a0 = x.x * __expf(-log_l[c0]);
    float a1 = x.y * __expf(-log_l[c0 + 1]);
    float ss = a0 * a0 + a1 * a1;
    #pragma unroll
    for (int o = 32; o; o >>= 1) ss += __shfl_down(ss, o);
    if (lane == 0) *nrm = ss;
    __bf16 h0 = (__bf16)a0, h1 = (__bf16)a1;
    __bf16 l0 = (__bf16)(a0 - (float)h0), l1 = (__bf16)(a1 - (float)h1);
    int m = lane >> 2;
    int c = m >> 2;
    int sh = m & 3;
    int sl = 4 | sh;
    int rs = row & 7;
    uint32_t offh = base + (uint32_t)c * 128u + (uint32_t)((sh ^ rs) * 16) + (uint32_t)(lane & 3) * 4u;
    uint32_t offl = base + (uint32_t)c * 128u + (uint32_t)((sl ^ rs) * 16) + (uint32_t)(lane & 3) * 4u;
    *(uint32_t*)(outbuf + offh) = pk2(h0, h1);
    *(uint32_t*)(outbuf + offl) = pk2(l0, l1);
}

// ---------------- launch 2: fast — DIRECT-GLOBAL stash frag GEMM, zero barriers ----------------
// Fragments are final bf16 in the stash; each wave loads its 16B frags straight
// from L2 (row&7 == lr&7, so the XOR unit index is a per-lane constant).
// No LDS, no barriers in the K-loop; overlap via 12 waves/CU TLP.
__global__ __launch_bounds__(256, 3) void fast_kernel(
    const char* __restrict__ stash,
    const int* __restrict__ task1, const int* __restrict__ task2,
    const float* __restrict__ log_theta_l, const float* __restrict__ bparam,
    float* __restrict__ C)
{
    const int t = threadIdx.x;
    const int lane = t & 63, wv = t >> 6;
    const int lr = lane & 15, lg = lane >> 4;
    const float* n1g = (const float*)(stash + NORM_OFF);
    const float* n2g = n1g + NN;
    float logt = log_theta_l[0];
    float bb = bparam[0];
    float lam = fminf(fmaxf(2.f / (1.f + __expf(bb)) - 1.f, 0.f), 1.f);
    int wg = blockIdx.x;

    const int uh = (lg ^ (lr & 7)) * 16;         // h-unit byte offset in chunk
    const int ul = ((4 | lg) ^ (lr & 7)) * 16;   // l-unit byte offset in chunk

    if (wg < 3840) {
        // ================= full 128x128 tile, tm 2..61 =================
        const int wr = wv >> 1, wc = wv & 1;
        int swz = (wg & 7) * 480 + (wg >> 3);     // bijective XCD chunking
        int tm = 2 + (swz >> 6);
        int tn = swz & 63;

        // per-lane row bases (mi steps +16 rows = +8192B)
        const char* Arow = stash + APRIME_OFF + (size_t)(tm * 128 + wr * 64 + lr) * 512;
        const char* Brow = stash + BPRIME_OFF + (size_t)(tn * 128 + wc * 64 + lr) * 512;

        f32x4 acc[4][4];
        #pragma unroll
        for (int i = 0; i < 4; ++i)
            #pragma unroll
            for (int j = 0; j < 4; ++j) acc[i][j] = (f32x4){0.f, 0.f, 0.f, 0.f};

        #pragma unroll
        for (int c = 0; c < 4; ++c) {
            bf16x8 ah[4], bh[4], xf[4];
            #pragma unroll
            for (int mi = 0; mi < 4; ++mi)
                ah[mi] = *(const bf16x8*)(Arow + mi * 8192 + c * 128 + uh);
            #pragma unroll
            for (int ni = 0; ni < 4; ++ni)
                bh[ni] = *(const bf16x8*)(Brow + ni * 8192 + c * 128 + uh);
            #pragma unroll
            for (int mi = 0; mi < 4; ++mi)
                #pragma unroll
                for (int ni = 0; ni < 4; ++ni)
                    acc[mi][ni] = __builtin_amdgcn_mfma_f32_16x16x32_bf16(
                        bh[ni], ah[mi], acc[mi][ni], 0, 0, 0);
            #pragma unroll
            for (int mi = 0; mi < 4; ++mi)
                xf[mi] = *(const bf16x8*)(Arow + mi * 8192 + c * 128 + ul);
            #pragma unroll
            for (int mi = 0; mi < 4; ++mi)
                #pragma unroll
                for (int ni = 0; ni < 4; ++ni)
                    acc[mi][ni] = __builtin_amdgcn_mfma_f32_16x16x32_bf16(
                        bh[ni], xf[mi], acc[mi][ni], 0, 0, 0);
            #pragma unroll
            for (int ni = 0; ni < 4; ++ni)
                xf[ni] = *(const bf16x8*)(Brow + ni * 8192 + c * 128 + ul);
            #pragma unroll
            for (int mi = 0; mi < 4; ++mi)
                #pragma unroll
                for (int ni = 0; ni < 4; ++ni)
                    acc[mi][ni] = __builtin_amdgcn_mfma_f32_16x16x32_bf16(
                        xf[ni], ah[mi], acc[mi][ni], 0, 0, 0);
        }

        int rbase = tm * 128, cbase = tn * 128;
        #pragma unroll
        for (int mi = 0; mi < 4; ++mi) {
            int rowl = wr * 64 + mi * 16 + lr;
            float n1v = n1g[rbase + rowl];
            int t1v = task1[rbase + rowl];
            #pragma unroll
            for (int ni = 0; ni < 4; ++ni) {
                int coll = wc * 64 + ni * 16 + lg * 4;
                f32x4 n2v = *(const f32x4*)(n2g + cbase + coll);
                i32x4 t2v = *(const i32x4*)(task2 + cbase + coll);
                f32x4 kv;
                #pragma unroll
                for (int rix = 0; rix < 4; ++rix) {
                    float s = fmaxf(n1v + n2v[rix] - 2.f * acc[mi][ni][rix], 0.f);
                    float k = __expf(fmaf(-0.5f, s, logt));
                    kv[rix] = (t1v != t2v[rix]) ? k * lam : k;
                }
                *(f32x4*)(C + (size_t)(rbase + rowl) * NN + cbase + coll) = kv;
            }
        }
    } else {
        // ================= quarter 64x64 tiles, tm = 62 (tail fill) =================
        int wq = wg - 3840;            // 0..255
        int tn = wq >> 2;
        int q = wq & 3;
        int arow0 = 62 * 128 + (q >> 1) * 64;
        int brow0 = tn * 128 + (q & 1) * 64;
        const int wr = wv >> 1, wc = wv & 1;   // 2x2 waves of 32x32

        const char* Arow = stash + APRIME_OFF + (size_t)(arow0 + wr * 32 + lr) * 512;
        const char* Brow = stash + BPRIME_OFF + (size_t)(brow0 + wc * 32 + lr) * 512;

        f32x4 acc[2][2];
        #pragma unroll
        for (int i = 0; i < 2; ++i)
            #pragma unroll
            for (int j = 0; j < 2; ++j) acc[i][j] = (f32x4){0.f, 0.f, 0.f, 0.f};

        #pragma unroll
        for (int c = 0; c < 4; ++c) {
            bf16x8 ah[2], bh[2], xf[2];
            #pragma unroll
            for (int mi = 0; mi < 2; ++mi)
                ah[mi] = *(const bf16x8*)(Arow + mi * 8192 + c * 128 + uh);
            #pragma unroll
            for (int ni = 0; ni < 2; ++ni)
                bh[ni] = *(const bf16x8*)(Brow + ni * 8192 + c * 128 + uh);
            #pragma unroll
            for (int mi = 0; mi < 2; ++mi)
                #pragma unroll
                for (int ni = 0; ni < 2; ++ni)
                    acc[mi][ni] = __builtin_amdgcn_mfma_f32_16x16x32_bf16(
                        bh[ni], ah[mi], acc[mi][ni], 0, 0, 0);
            #pragma unroll
            for (int mi = 0; mi < 2; ++mi)
                xf[mi] = *(const bf16x8*)(Arow + mi * 8192 + c * 128 + ul);
            #pragma unroll
            for (int mi = 0; mi < 2; ++mi)
                #pragma unroll
                for (int ni = 0; ni < 2; ++ni)
                    acc[mi][ni] = __builtin_amdgcn_mfma_f32_16x16x32_bf16(
                        bh[ni], xf[mi], acc[mi][ni], 0, 0, 0);
            #pragma unroll
            for (int ni = 0; ni < 2; ++ni)
                xf[ni] = *(const bf16x8*)(Brow + ni * 8192 + c * 128 + ul);
            #pragma unroll
            for (int mi = 0; mi < 2; ++mi)
                #pragma unroll
                for (int ni = 0; ni < 2; ++ni)
                    acc[mi][ni] = __builtin_amdgcn_mfma_f32_16x16x32_bf16(
                        xf[ni], ah[mi], acc[mi][ni], 0, 0, 0);
        }

        #pragma unroll
        for (int mi = 0; mi < 2; ++mi) {
            int rowl = wr * 32 + mi * 16 + lr;
            float n1v = n1g[arow0 + rowl];
            int t1v = task1[arow0 + rowl];
            #pragma unroll
            for (int ni = 0; ni < 2; ++ni) {
                int coll = wc * 32 + ni * 16 + lg * 4;
                f32x4 n2v = *(const f32x4*)(n2g + brow0 + coll);
                i32x4 t2v = *(const i32x4*)(task2 + brow0 + coll);
                f32x4 kv;
                #pragma unroll
                for (int rix = 0; rix < 4; ++rix) {
                    float s = fmaxf(n1v + n2v[rix] - 2.f * acc[mi][ni][rix], 0.f);
                    float k = __expf(fmaf(-0.5f, s, logt));
                    kv[rix] = (t1v != t2v[rix]) ? k * lam : k;
                }
                *(f32x4*)(C + (size_t)(arow0 + rowl) * NN + brow0 + coll) = kv;
            }
        }
    }
}

// ---------------- launch 3: slow — R7 pattern at 64x64 quarters, tm in {0,1,63} (R15 verbatim) ----------------
#define RSTRIDE 80
#define SQ_AH 0
#define SQ_AL 5120
#define SQ_BH 10240
#define SQ_BL 15360
#define SQ_ILS 20480
#define SQ_N1  20992
#define SQ_N2  21504
#define SQ_TOT 22016

__device__ __forceinline__ void split4(f32x4 x, uint2& hi, uint2& lo) {
    __bf16 h0 = (__bf16)x[0], h1 = (__bf16)x[1], h2 = (__bf16)x[2], h3 = (__bf16)x[3];
    hi.x = pk2(h0, h1); hi.y = pk2(h2, h3);
    __bf16 l0 = (__bf16)(x[0] - (float)h0);
    __bf16 l1 = (__bf16)(x[1] - (float)h1);
    __bf16 l2 = (__bf16)(x[2] - (float)h2);
    __bf16 l3 = (__bf16)(x[3] - (float)h3);
    lo.x = pk2(l0, l1); lo.y = pk2(l2, l3);
}

__device__ __forceinline__ void lds_barrier() {
    asm volatile("s_waitcnt lgkmcnt(0)" ::: "memory");
    __builtin_amdgcn_sched_barrier(0);
    __builtin_amdgcn_s_barrier();
    __builtin_amdgcn_sched_barrier(0);
}

__global__ __launch_bounds__(256, 3) void slow_kernel(
    const float* __restrict__ X1, const float* __restrict__ X2,
    const float* __restrict__ log_l,
    const float* __restrict__ log_theta_l, const float* __restrict__ bparam,
    const int* __restrict__ task1, const int* __restrict__ task2,
    float* __restrict__ C)
{
    __shared__ __align__(16) char smem[SQ_TOT];
    float* const ils = (float*)(smem + SQ_ILS);
    float* const n1s = (float*)(smem + SQ_N1);
    float* const n2s = (float*)(smem + SQ_N2);

    const int t = threadIdx.x;
    const int lane = t & 63;
    const int wv = t >> 6;
    const int wr = wv >> 1, wc = wv & 1;   // 2x2 waves of 32x32
    const int lr = lane & 15, lg = lane >> 4;
    const int kq = t & 7;
    const int rg = t >> 3;                 // 0..31

    int wg = blockIdx.x;                   // 0..767
    int ti = wg >> 2;                      // 0..191
    int tsel = ti >> 6;
    int tm = (tsel == 2) ? 63 : tsel;
    int tn = ti & 63;
    int q = wg & 3;
    int row0 = tm * 128 + (q >> 1) * 64;
    int col0 = tn * 128 + (q & 1) * 64;

    const float* Ag = X1 + (size_t)row0 * DDIM;
    const float* Bg = X2 + (size_t)col0 * DDIM;

    if (t < 128) ils[t] = __expf(-log_l[t]);

    f32x4 aV[2], bV[2];
    #pragma unroll
    for (int e = 0; e < 2; ++e) {
        aV[e] = *(const f32x4*)(Ag + (size_t)(e * 32 + rg) * DDIM + kq * 4);
        bV[e] = *(const f32x4*)(Bg + (size_t)(e * 32 + rg) * DDIM + kq * 4);
    }
    __syncthreads();

    float nA[2] = {0.f, 0.f};
    float nB[2] = {0.f, 0.f};
    f32x4 acc[2][2];
    #pragma unroll
    for (int i = 0; i < 2; ++i)
        #pragma unroll
        for (int j = 0; j < 2; ++j) acc[i][j] = (f32x4){0.f, 0.f, 0.f, 0.f};

    for (int c = 0; c < 4; ++c) {
        {
            f32x4 il4 = *(const f32x4*)(ils + c * 32 + kq * 4);
            #pragma unroll
            for (int e = 0; e < 2; ++e) {
                int rr = e * 32 + rg;
                f32x4 xa = aV[e] * il4;
                f32x4 xb = bV[e] * il4;
                nA[e] += xa[0]*xa[0] + xa[1]*xa[1] + xa[2]*xa[2] + xa[3]*xa[3];
                nB[e] += xb[0]*xb[0] + xb[1]*xb[1] + xb[2]*xb[2] + xb[3]*xb[3];
                uint2 hA, lA, hB, lB;
                split4(xa, hA, lA);
                split4(xb, hB, lB);
                int boff = rr * RSTRIDE + kq * 8;
                *(uint2*)(smem + SQ_AH + boff) = hA;
                *(uint2*)(smem + SQ_AL + boff) = lA;
                *(uint2*)(smem + SQ_BH + boff) = hB;
                *(uint2*)(smem + SQ_BL + boff) = lB;
            }
        }
        if (c < 3) {
            #pragma unroll
            for (int e = 0; e < 2; ++e) {
                aV[e] = *(const f32x4*)(Ag + (size_t)(e * 32 + rg) * DDIM + (c + 1) * 32 + kq * 4);
                bV[e] = *(const f32x4*)(Bg + (size_t)(e * 32 + rg) * DDIM + (c + 1) * 32 + kq * 4);
            }
        }
        lds_barrier();
        {
            bf16x8 ah[2], bh[2], xf[2];
            #pragma unroll
            for (int mi = 0; mi < 2; ++mi) {
                int off = (wr * 32 + mi * 16 + lr) * RSTRIDE + lg * 16;
                ah[mi] = *(const bf16x8*)(smem + SQ_AH + off);
            }
            #pragma unroll
            for (int ni = 0; ni < 2; ++ni) {
                int off = (wc * 32 + ni * 16 + lr) * RSTRIDE + lg * 16;
                bh[ni] = *(const bf16x8*)(smem + SQ_BH + off);
            }
            #pragma unroll
            for (int mi = 0; mi < 2; ++mi)
                #pragma unroll
                for (int ni = 0; ni < 2; ++ni)
                    acc[mi][ni] = __builtin_amdgcn_mfma_f32_16x16x32_bf16(bh[ni], ah[mi], acc[mi][ni], 0, 0, 0);
            #pragma unroll
            for (int mi = 0; mi < 2; ++mi) {
                int off = (wr * 32 + mi * 16 + lr) * RSTRIDE + lg * 16;
                xf[mi] = *(const bf16x8*)(smem + SQ_AL + off);
            }
            #pragma unroll
            for (int mi = 0; mi < 2; ++mi)
                #pragma unroll
                for (int ni = 0; ni < 2; ++ni)
                    acc[mi][ni] = __builtin_amdgcn_mfma_f32_16x16x32_bf16(bh[ni], xf[mi], acc[mi][ni], 0, 0, 0);
            #pragma unroll
            for (int ni = 0; ni < 2; ++ni) {
                int off = (wc * 32 + ni * 16 + lr) * RSTRIDE + lg * 16;
                xf[ni] = *(const bf16x8*)(smem + SQ_BL + off);
            }
            #pragma unroll
            for (int mi = 0; mi < 2; ++mi)
                #pragma unroll
                for (int ni = 0; ni < 2; ++ni)
                    acc[mi][ni] = __builtin_amdgcn_mfma_f32_16x16x32_bf16(xf[ni], ah[mi], acc[mi][ni], 0, 0, 0);
        }
        lds_barrier();
    }

    #pragma unroll
    for (int e = 0; e < 2; ++e) {
        #pragma unroll
        for (int off = 1; off < 8; off <<= 1) {
            nA[e] += __shfl_xor(nA[e], off);
            nB[e] += __shfl_xor(nB[e], off);
        }
    }
    if (kq == 0) {
        #pragma unroll
        for (int e = 0; e < 2; ++e) {
            n1s[e * 32 + rg] = nA[e];
            n2s[e * 32 + rg] = nB[e];
        }
    }
    __syncthreads();

    float logt = log_theta_l[0];
    float bb = bparam[0];
    float lam = fminf(fmaxf(2.f / (1.f + __expf(bb)) - 1.f, 0.f), 1.f);

    #pragma unroll
    for (int mi = 0; mi < 2; ++mi) {
        int rowl = wr * 32 + mi * 16 + lr;
        float n1v = n1s[rowl];
        int t1v = task1[row0 + rowl];
        #pragma unroll
        for (int ni = 0; ni < 2; ++ni) {
            int coll = wc * 32 + ni * 16 + lg * 4;
            f32x4 n2v = *(const f32x4*)(n2s + coll);
            i32x4 t2v = *(const i32x4*)(task2 + col0 + coll);
            f32x4 kv;
            #pragma unroll
            for (int rix = 0; rix < 4; ++rix) {
                float s = fmaxf(n1v + n2v[rix] - 2.f * acc[mi][ni][rix], 0.f);
                float k = __expf(fmaf(-0.5f, s, logt));
                kv[rix] = (t1v != t2v[rix]) ? k * lam : k;
            }
            *(f32x4*)(C + (size_t)(row0 + rowl) * NN + col0 + coll) = kv;
        }
    }
}

extern "C" void kernel_launch(void* const* d_in, const int* in_sizes, int n_in,
                              void* d_out, int out_size, void* d_ws, size_t ws_size,
                              hipStream_t stream)
{
    const float* X1 = (const float*)d_in[0];
    const float* X2 = (const float*)d_in[1];
    const float* log_l = (const float*)d_in[2];
    const float* log_theta = (const float*)d_in[3];
    const float* bp = (const float*)d_in[4];
    const int* t1 = (const int*)d_in[5];
    const int* t2 = (const int*)d_in[6];
    float* C = (float*)d_out;
    (void)d_ws; (void)ws_size; (void)in_sizes; (void)n_in; (void)out_size;

    prep_kernel<<<4096, 256, 0, stream>>>(X1, X2, log_l, (char*)d_out);
    fast_kernel<<<4096, 256, 0, stream>>>((const char*)d_out, t1, t2, log_theta, bp, C);
    slow_kernel<<<768, 256, 0, stream>>>(X1, X2, log_l, log_theta, bp, t1, t2, C);
}

// Round 18
// 99.434 us; speedup vs baseline: 1.2302x; 1.2302x over previous
//
#include <hip/hip_runtime.h>
#include <stdint.h>

typedef float f32x4 __attribute__((ext_vector_type(4)));
typedef int   i32x4 __attribute__((ext_vector_type(4)));
typedef __bf16 bf16x8 __attribute__((ext_vector_type(8)));

#define NN 8192
#define DDIM 128

// ---- stash layout inside d_out (bytes) ----
// Row = 512B: 4 chunks x [h(32 cols)=64B | l(32 cols)=64B], 16B units
// XOR-swizzled WITHIN each 8-unit chunk by (row&7).
// A'(8192x512B) = C rows 0..127 ; B' = C rows 128..255
// norms n1[8192],n2[8192] f32 = last 64KB = C rows 8190..8191
#define APRIME_OFF 0u
#define BPRIME_OFF (8192u*512u)
#define NORM_OFF   (268435456u - 65536u)

__device__ __forceinline__ uint32_t pk2(__bf16 a, __bf16 b) {
    return (uint32_t)__builtin_bit_cast(unsigned short, a)
         | ((uint32_t)__builtin_bit_cast(unsigned short, b) << 16);
}

__device__ __forceinline__ void gload_lds16(const void* g, void* l) {
    __builtin_amdgcn_global_load_lds(
        (const __attribute__((address_space(1))) uint32_t*)g,
        (__attribute__((address_space(3))) uint32_t*)l,
        16, 0, 0);
}

// ---------------- launch 1: prep — split each row ONCE (R13-R15 verbatim) ----------------
__global__ __launch_bounds__(256) void prep_kernel(
    const float* __restrict__ X1, const float* __restrict__ X2,
    const float* __restrict__ log_l, char* __restrict__ outbuf)
{
    int t = threadIdx.x, wave = t >> 6, lane = t & 63;
    int row = blockIdx.x * 4 + wave;          // 0..16383
    const float* X; uint32_t base; float* nrm;
    if (row < NN) {
        X = X1 + (size_t)row * DDIM;
        base = APRIME_OFF + (uint32_t)row * 512u;
        nrm = (float*)(outbuf + NORM_OFF) + row;
    } else {
        int r2 = row - NN;
        X = X2 + (size_t)r2 * DDIM;
        base = BPRIME_OFF + (uint32_t)r2 * 512u;
        nrm = (float*)(outbuf + NORM_OFF) + NN + r2;
    }
    int c0 = lane * 2;
    float2 x = *(const float2*)(X + c0);
    float a0 = x.x * __expf(-log_l[c0]);
    float a1 = x.y * __expf(-log_l[c0 + 1]);
    float ss = a0 * a0 + a1 * a1;
    #pragma unroll
    for (int o = 32; o; o >>= 1) ss += __shfl_down(ss, o);
    if (lane == 0) *nrm = ss;
    __bf16 h0 = (__bf16)a0, h1 = (__bf16)a1;
    __bf16 l0 = (__bf16)(a0 - (float)h0), l1 = (__bf16)(a1 - (float)h1);
    int m = lane >> 2;
    int c = m >> 2;
    int sh = m & 3;
    int sl = 4 | sh;
    int rs = row & 7;
    uint32_t offh = base + (uint32_t)c * 128u + (uint32_t)((sh ^ rs) * 16) + (uint32_t)(lane & 3) * 4u;
    uint32_t offl = base + (uint32_t)c * 128u + (uint32_t)((sl ^ rs) * 16) + (uint32_t)(lane & 3) * 4u;
    *(uint32_t*)(outbuf + offh) = pk2(h0, h1);
    *(uint32_t*)(outbuf + offl) = pk2(l0, l1);
}

// ---------------- launch 2: fast — stash GEMM, 2-PHASE double-buffered staging ----------------
// STAGE(c+1 -> buf (c+1)&1) issued BEFORE FRAGMM(chunk c from buf c&1);
// one __syncthreads (full drain + barrier) per chunk. Buffer overwrite always
// one barrier after its last reader. NT stores keep C out of L2.
__global__ __launch_bounds__(256, 2) void fast_kernel(
    const char* __restrict__ stash,
    const int* __restrict__ task1, const int* __restrict__ task2,
    const float* __restrict__ log_theta_l, const float* __restrict__ bparam,
    float* __restrict__ C)
{
    __shared__ __align__(16) char smem[65536];   // 2 x {A 16K | B 16K}
    const int t = threadIdx.x;
    const int lane = t & 63, wv = t >> 6;
    const int lr = lane & 15, lg = lane >> 4;
    const float* n1g = (const float*)(stash + NORM_OFF);
    const float* n2g = n1g + NN;
    float logt = log_theta_l[0];
    float bb = bparam[0];
    float lam = fminf(fmaxf(2.f / (1.f + __expf(bb)) - 1.f, 0.f), 1.f);
    int wg = blockIdx.x;

    if (wg < 3840) {
        // ================= full 128x128 tile, tm 2..61 =================
        const int wr = wv >> 1, wc = wv & 1;
        int swz = (wg & 7) * 480 + (wg >> 3);     // bijective XCD chunking
        int tm = 2 + (swz >> 6);
        int tn = swz & 63;
        const char* Abase = stash + APRIME_OFF + (size_t)tm * 128 * 512;
        const char* Bbase = stash + BPRIME_OFF + (size_t)tn * 128 * 512;

        f32x4 acc[4][4];
        #pragma unroll
        for (int i = 0; i < 4; ++i)
            #pragma unroll
            for (int j = 0; j < 4; ++j) acc[i][j] = (f32x4){0.f, 0.f, 0.f, 0.f};

        #define STAGE_F(c, buf) do {                                              \
            _Pragma("unroll")                                                     \
            for (int i = 0; i < 4; ++i) {                                         \
                int l = t + i * 256;                                              \
                gload_lds16(Abase + (size_t)(l >> 3) * 512 + (c) * 128 + (l & 7) * 16,\
                            smem + (buf) * 32768 + l * 16);                       \
                gload_lds16(Bbase + (size_t)(l >> 3) * 512 + (c) * 128 + (l & 7) * 16,\
                            smem + (buf) * 32768 + 16384 + l * 16);               \
            }                                                                     \
        } while (0)

        #define FRAGMM_F(buf) do {                                                \
            const char* tb_ = smem + (buf) * 32768;                               \
            bf16x8 ah[4], bh[4], xf[4];                                           \
            _Pragma("unroll")                                                     \
            for (int mi = 0; mi < 4; ++mi) {                                      \
                int row = wr * 64 + mi * 16 + lr;                                 \
                ah[mi] = *(const bf16x8*)(tb_ + row * 128 + ((lg ^ (row & 7)) * 16));\
            }                                                                     \
            _Pragma("unroll")                                                     \
            for (int ni = 0; ni < 4; ++ni) {                                      \
                int row = wc * 64 + ni * 16 + lr;                                 \
                bh[ni] = *(const bf16x8*)(tb_ + 16384 + row * 128                 \
                          + ((lg ^ (row & 7)) * 16));                             \
            }                                                                     \
            _Pragma("unroll")                                                     \
            for (int mi = 0; mi < 4; ++mi)                                        \
                _Pragma("unroll")                                                 \
                for (int ni = 0; ni < 4; ++ni)                                    \
                    acc[mi][ni] = __builtin_amdgcn_mfma_f32_16x16x32_bf16(        \
                        bh[ni], ah[mi], acc[mi][ni], 0, 0, 0);                    \
            _Pragma("unroll")                                                     \
            for (int mi = 0; mi < 4; ++mi) {                                      \
                int row = wr * 64 + mi * 16 + lr;                                 \
                xf[mi] = *(const bf16x8*)(tb_ + row * 128                         \
                          + (((4 | lg) ^ (row & 7)) * 16));                       \
            }                                                                     \
            _Pragma("unroll")                                                     \
            for (int mi = 0; mi < 4; ++mi)                                        \
                _Pragma("unroll")                                                 \
                for (int ni = 0; ni < 4; ++ni)                                    \
                    acc[mi][ni] = __builtin_amdgcn_mfma_f32_16x16x32_bf16(        \
                        bh[ni], xf[mi], acc[mi][ni], 0, 0, 0);                    \
            _Pragma("unroll")                                                     \
            for (int ni = 0; ni < 4; ++ni) {                                      \
                int row = wc * 64 + ni * 16 + lr;                                 \
                xf[ni] = *(const bf16x8*)(tb_ + 16384 + row * 128                 \
                          + (((4 | lg) ^ (row & 7)) * 16));                       \
            }                                                                     \
            _Pragma("unroll")                                                     \
            for (int mi = 0; mi < 4; ++mi)                                        \
                _Pragma("unroll")                                                 \
                for (int ni = 0; ni < 4; ++ni)                                    \
                    acc[mi][ni] = __builtin_amdgcn_mfma_f32_16x16x32_bf16(        \
                        xf[ni], ah[mi], acc[mi][ni], 0, 0, 0);                    \
        } while (0)

        // 2-phase pipeline; buffer index = chunk & 1 (R17 bug: was chunk index)
        STAGE_F(0, 0);
        __syncthreads();                 // stage(0) complete
        STAGE_F(1, 1);  FRAGMM_F(0);  __syncthreads();   // chunk0 from buf0
        STAGE_F(2, 0);  FRAGMM_F(1);  __syncthreads();   // chunk1 from buf1
        STAGE_F(3, 1);  FRAGMM_F(0);  __syncthreads();   // chunk2 from buf0
                        FRAGMM_F(1);                     // chunk3 from buf1

        int rbase = tm * 128, cbase = tn * 128;
        #pragma unroll
        for (int mi = 0; mi < 4; ++mi) {
            int rowl = wr * 64 + mi * 16 + lr;
            float n1v = n1g[rbase + rowl];
            int t1v = task1[rbase + rowl];
            #pragma unroll
            for (int ni = 0; ni < 4; ++ni) {
                int coll = wc * 64 + ni * 16 + lg * 4;
                f32x4 n2v = *(const f32x4*)(n2g + cbase + coll);
                i32x4 t2v = *(const i32x4*)(task2 + cbase + coll);
                f32x4 kv;
                #pragma unroll
                for (int rix = 0; rix < 4; ++rix) {
                    float s = fmaxf(n1v + n2v[rix] - 2.f * acc[mi][ni][rix], 0.f);
                    float k = __expf(fmaf(-0.5f, s, logt));
                    kv[rix] = (t1v != t2v[rix]) ? k * lam : k;
                }
                __builtin_nontemporal_store(kv,
                    (f32x4*)(C + (size_t)(rbase + rowl) * NN + cbase + coll));
            }
        }
        #undef STAGE_F
        #undef FRAGMM_F
    } else {
        // ================= quarter 64x64 tiles, tm = 62 (tail fill) =================
        int wq = wg - 3840;            // 0..255
        int tn = wq >> 2;
        int q = wq & 3;
        int arow0 = 62 * 128 + (q >> 1) * 64;
        int brow0 = tn * 128 + (q & 1) * 64;
        const int wr = wv >> 1, wc = wv & 1;   // 2x2 waves of 32x32
        const char* Abase = stash + APRIME_OFF + (size_t)arow0 * 512;
        const char* Bbase = stash + BPRIME_OFF + (size_t)brow0 * 512;

        f32x4 acc[2][2];
        #pragma unroll
        for (int i = 0; i < 2; ++i)
            #pragma unroll
            for (int j = 0; j < 2; ++j) acc[i][j] = (f32x4){0.f, 0.f, 0.f, 0.f};

        #define STAGE_Q(c, buf) do {                                              \
            _Pragma("unroll")                                                     \
            for (int i = 0; i < 2; ++i) {                                         \
                int l = t + i * 256;                                              \
                gload_lds16(Abase + (size_t)(l >> 3) * 512 + (c) * 128 + (l & 7) * 16,\
                            smem + (buf) * 32768 + l * 16);                       \
                gload_lds16(Bbase + (size_t)(l >> 3) * 512 + (c) * 128 + (l & 7) * 16,\
                            smem + (buf) * 32768 + 8192 + l * 16);               \
            }                                                                     \
        } while (0)

        #define FRAGMM_Q(buf) do {                                                \
            const char* tb_ = smem + (buf) * 32768;                               \
            bf16x8 ah[2], bh[2], xf[2];                                           \
            _Pragma("unroll")                                                     \
            for (int mi = 0; mi < 2; ++mi) {                                      \
                int row = wr * 32 + mi * 16 + lr;                                 \
                ah[mi] = *(const bf16x8*)(tb_ + row * 128 + ((lg ^ (row & 7)) * 16));\
            }                                                                     \
            _Pragma("unroll")                                                     \
            for (int ni = 0; ni < 2; ++ni) {                                      \
                int row = wc * 32 + ni * 16 + lr;                                 \
                bh[ni] = *(const bf16x8*)(tb_ + 8192 + row * 128                  \
                          + ((lg ^ (row & 7)) * 16));                             \
            }                                                                     \
            _Pragma("unroll")                                                     \
            for (int mi = 0; mi < 2; ++mi)                                        \
                _Pragma("unroll")                                                 \
                for (int ni = 0; ni < 2; ++ni)                                    \
                    acc[mi][ni] = __builtin_amdgcn_mfma_f32_16x16x32_bf16(        \
                        bh[ni], ah[mi], acc[mi][ni], 0, 0, 0);                    \
            _Pragma("unroll")                                                     \
            for (int mi = 0; mi < 2; ++mi) {                                      \
                int row = wr * 32 + mi * 16 + lr;                                 \
                xf[mi] = *(const bf16x8*)(tb_ + row * 128                         \
                          + (((4 | lg) ^ (row & 7)) * 16));                       \
            }                                                                     \
            _Pragma("unroll")                                                     \
            for (int mi = 0; mi < 2; ++mi)                                        \
                _Pragma("unroll")                                                 \
                for (int ni = 0; ni < 2; ++ni)                                    \
                    acc[mi][ni] = __builtin_amdgcn_mfma_f32_16x16x32_bf16(        \
                        bh[ni], xf[mi], acc[mi][ni], 0, 0, 0);                    \
            _Pragma("unroll")                                                     \
            for (int ni = 0; ni < 2; ++ni) {                                      \
                int row = wc * 32 + ni * 16 + lr;                                 \
                xf[ni] = *(const bf16x8*)(tb_ + 8192 + row * 128                  \
                          + (((4 | lg) ^ (row & 7)) * 16));                       \
            }                                                                     \
            _Pragma("unroll")                                                     \
            for (int mi = 0; mi < 2; ++mi)                                        \
                _Pragma("unroll")                                                 \
                for (int ni = 0; ni < 2; ++ni)                                    \
                    acc[mi][ni] = __builtin_amdgcn_mfma_f32_16x16x32_bf16(        \
                        xf[ni], ah[mi], acc[mi][ni], 0, 0, 0);                    \
        } while (0)

        STAGE_Q(0, 0);
        __syncthreads();
        STAGE_Q(1, 1);  FRAGMM_Q(0);  __syncthreads();   // chunk0 / buf0
        STAGE_Q(2, 0);  FRAGMM_Q(1);  __syncthreads();   // chunk1 / buf1
        STAGE_Q(3, 1);  FRAGMM_Q(0);  __syncthreads();   // chunk2 / buf0
                        FRAGMM_Q(1);                     // chunk3 / buf1

        #pragma unroll
        for (int mi = 0; mi < 2; ++mi) {
            int rowl = wr * 32 + mi * 16 + lr;
            float n1v = n1g[arow0 + rowl];
            int t1v = task1[arow0 + rowl];
            #pragma unroll
            for (int ni = 0; ni < 2; ++ni) {
                int coll = wc * 32 + ni * 16 + lg * 4;
                f32x4 n2v = *(const f32x4*)(n2g + brow0 + coll);
                i32x4 t2v = *(const i32x4*)(task2 + brow0 + coll);
                f32x4 kv;
                #pragma unroll
                for (int rix = 0; rix < 4; ++rix) {
                    float s = fmaxf(n1v + n2v[rix] - 2.f * acc[mi][ni][rix], 0.f);
                    float k = __expf(fmaf(-0.5f, s, logt));
                    kv[rix] = (t1v != t2v[rix]) ? k * lam : k;
                }
                __builtin_nontemporal_store(kv,
                    (f32x4*)(C + (size_t)(arow0 + rowl) * NN + brow0 + coll));
            }
        }
        #undef STAGE_Q
        #undef FRAGMM_Q
    }
}

// ---------------- launch 3: slow — R7 pattern at 64x64 quarters, tm in {0,1,63} (R15 verbatim) ----------------
#define RSTRIDE 80
#define SQ_AH 0
#define SQ_AL 5120
#define SQ_BH 10240
#define SQ_BL 15360
#define SQ_ILS 20480
#define SQ_N1  20992
#define SQ_N2  21504
#define SQ_TOT 22016

__device__ __forceinline__ void split4(f32x4 x, uint2& hi, uint2& lo) {
    __bf16 h0 = (__bf16)x[0], h1 = (__bf16)x[1], h2 = (__bf16)x[2], h3 = (__bf16)x[3];
    hi.x = pk2(h0, h1); hi.y = pk2(h2, h3);
    __bf16 l0 = (__bf16)(x[0] - (float)h0);
    __bf16 l1 = (__bf16)(x[1] - (float)h1);
    __bf16 l2 = (__bf16)(x[2] - (float)h2);
    __bf16 l3 = (__bf16)(x[3] - (float)h3);
    lo.x = pk2(l0, l1); lo.y = pk2(l2, l3);
}

__device__ __forceinline__ void lds_barrier() {
    asm volatile("s_waitcnt lgkmcnt(0)" ::: "memory");
    __builtin_amdgcn_sched_barrier(0);
    __builtin_amdgcn_s_barrier();
    __builtin_amdgcn_sched_barrier(0);
}

__global__ __launch_bounds__(256, 3) void slow_kernel(
    const float* __restrict__ X1, const float* __restrict__ X2,
    const float* __restrict__ log_l,
    const float* __restrict__ log_theta_l, const float* __restrict__ bparam,
    const int* __restrict__ task1, const int* __restrict__ task2,
    float* __restrict__ C)
{
    __shared__ __align__(16) char smem[SQ_TOT];
    float* const ils = (float*)(smem + SQ_ILS);
    float* const n1s = (float*)(smem + SQ_N1);
    float* const n2s = (float*)(smem + SQ_N2);

    const int t = threadIdx.x;
    const int lane = t & 63;
    const int wv = t >> 6;
    const int wr = wv >> 1, wc = wv & 1;   // 2x2 waves of 32x32
    const int lr = lane & 15, lg = lane >> 4;
    const int kq = t & 7;
    const int rg = t >> 3;                 // 0..31

    int wg = blockIdx.x;                   // 0..767
    int ti = wg >> 2;                      // 0..191
    int tsel = ti >> 6;
    int tm = (tsel == 2) ? 63 : tsel;
    int tn = ti & 63;
    int q = wg & 3;
    int row0 = tm * 128 + (q >> 1) * 64;
    int col0 = tn * 128 + (q & 1) * 64;

    const float* Ag = X1 + (size_t)row0 * DDIM;
    const float* Bg = X2 + (size_t)col0 * DDIM;

    if (t < 128) ils[t] = __expf(-log_l[t]);

    f32x4 aV[2], bV[2];
    #pragma unroll
    for (int e = 0; e < 2; ++e) {
        aV[e] = *(const f32x4*)(Ag + (size_t)(e * 32 + rg) * DDIM + kq * 4);
        bV[e] = *(const f32x4*)(Bg + (size_t)(e * 32 + rg) * DDIM + kq * 4);
    }
    __syncthreads();

    float nA[2] = {0.f, 0.f};
    float nB[2] = {0.f, 0.f};
    f32x4 acc[2][2];
    #pragma unroll
    for (int i = 0; i < 2; ++i)
        #pragma unroll
        for (int j = 0; j < 2; ++j) acc[i][j] = (f32x4){0.f, 0.f, 0.f, 0.f};

    for (int c = 0; c < 4; ++c) {
        {
            f32x4 il4 = *(const f32x4*)(ils + c * 32 + kq * 4);
            #pragma unroll
            for (int e = 0; e < 2; ++e) {
                int rr = e * 32 + rg;
                f32x4 xa = aV[e] * il4;
                f32x4 xb = bV[e] * il4;
                nA[e] += xa[0]*xa[0] + xa[1]*xa[1] + xa[2]*xa[2] + xa[3]*xa[3];
                nB[e] += xb[0]*xb[0] + xb[1]*xb[1] + xb[2]*xb[2] + xb[3]*xb[3];
                uint2 hA, lA, hB, lB;
                split4(xa, hA, lA);
                split4(xb, hB, lB);
                int boff = rr * RSTRIDE + kq * 8;
                *(uint2*)(smem + SQ_AH + boff) = hA;
                *(uint2*)(smem + SQ_AL + boff) = lA;
                *(uint2*)(smem + SQ_BH + boff) = hB;
                *(uint2*)(smem + SQ_BL + boff) = lB;
            }
        }
        if (c < 3) {
            #pragma unroll
            for (int e = 0; e < 2; ++e) {
                aV[e] = *(const f32x4*)(Ag + (size_t)(e * 32 + rg) * DDIM + (c + 1) * 32 + kq * 4);
                bV[e] = *(const f32x4*)(Bg + (size_t)(e * 32 + rg) * DDIM + (c + 1) * 32 + kq * 4);
            }
        }
        lds_barrier();
        {
            bf16x8 ah[2], bh[2], xf[2];
            #pragma unroll
            for (int mi = 0; mi < 2; ++mi) {
                int off = (wr * 32 + mi * 16 + lr) * RSTRIDE + lg * 16;
                ah[mi] = *(const bf16x8*)(smem + SQ_AH + off);
            }
            #pragma unroll
            for (int ni = 0; ni < 2; ++ni) {
                int off = (wc * 32 + ni * 16 + lr) * RSTRIDE + lg * 16;
                bh[ni] = *(const bf16x8*)(smem + SQ_BH + off);
            }
            #pragma unroll
            for (int mi = 0; mi < 2; ++mi)
                #pragma unroll
                for (int ni = 0; ni < 2; ++ni)
                    acc[mi][ni] = __builtin_amdgcn_mfma_f32_16x16x32_bf16(bh[ni], ah[mi], acc[mi][ni], 0, 0, 0);
            #pragma unroll
            for (int mi = 0; mi < 2; ++mi) {
                int off = (wr * 32 + mi * 16 + lr) * RSTRIDE + lg * 16;
                xf[mi] = *(const bf16x8*)(smem + SQ_AL + off);
            }
            #pragma unroll
            for (int mi = 0; mi < 2; ++mi)
                #pragma unroll
                for (int ni = 0; ni < 2; ++ni)
                    acc[mi][ni] = __builtin_amdgcn_mfma_f32_16x16x32_bf16(bh[ni], xf[mi], acc[mi][ni], 0, 0, 0);
            #pragma unroll
            for (int ni = 0; ni < 2; ++ni) {
                int off = (wc * 32 + ni * 16 + lr) * RSTRIDE + lg * 16;
                xf[ni] = *(const bf16x8*)(smem + SQ_BL + off);
            }
            #pragma unroll
            for (int mi = 0; mi < 2; ++mi)
                #pragma unroll
                for (int ni = 0; ni < 2; ++ni)
                    acc[mi][ni] = __builtin_amdgcn_mfma_f32_16x16x32_bf16(xf[ni], ah[mi], acc[mi][ni], 0, 0, 0);
        }
        lds_barrier();
    }

    #pragma unroll
    for (int e = 0; e < 2; ++e) {
        #pragma unroll
        for (int off = 1; off < 8; off <<= 1) {
            nA[e] += __shfl_xor(nA[e], off);
            nB[e] += __shfl_xor(nB[e], off);
        }
    }
    if (kq == 0) {
        #pragma unroll
        for (int e = 0; e < 2; ++e) {
            n1s[e * 32 + rg] = nA[e];
            n2s[e * 32 + rg] = nB[e];
        }
    }
    __syncthreads();

    float logt = log_theta_l[0];
    float bb = bparam[0];
    float lam = fminf(fmaxf(2.f / (1.f + __expf(bb)) - 1.f, 0.f), 1.f);

    #pragma unroll
    for (int mi = 0; mi < 2; ++mi) {
        int rowl = wr * 32 + mi * 16 + lr;
        float n1v = n1s[rowl];
        int t1v = task1[row0 + rowl];
        #pragma unroll
        for (int ni = 0; ni < 2; ++ni) {
            int coll = wc * 32 + ni * 16 + lg * 4;
            f32x4 n2v = *(const f32x4*)(n2s + coll);
            i32x4 t2v = *(const i32x4*)(task2 + col0 + coll);
            f32x4 kv;
            #pragma unroll
            for (int rix = 0; rix < 4; ++rix) {
                float s = fmaxf(n1v + n2v[rix] - 2.f * acc[mi][ni][rix], 0.f);
                float k = __expf(fmaf(-0.5f, s, logt));
                kv[rix] = (t1v != t2v[rix]) ? k * lam : k;
            }
            *(f32x4*)(C + (size_t)(row0 + rowl) * NN + col0 + coll) = kv;
        }
    }
}

extern "C" void kernel_launch(void* const* d_in, const int* in_sizes, int n_in,
                              void* d_out, int out_size, void* d_ws, size_t ws_size,
                              hipStream_t stream)
{
    const float* X1 = (const float*)d_in[0];
    const float* X2 = (const float*)d_in[1];
    const float* log_l = (const float*)d_in[2];
    const float* log_theta = (const float*)d_in[3];
    const float* bp = (const float*)d_in[4];
    const int* t1 = (const int*)d_in[5];
    const int* t2 = (const int*)d_in[6];
    float* C = (float*)d_out;
    (void)d_ws; (void)ws_size; (void)in_sizes; (void)n_in; (void)out_size;

    prep_kernel<<<4096, 256, 0, stream>>>(X1, X2, log_l, (char*)d_out);
    fast_kernel<<<4096, 256, 0, stream>>>((const char*)d_out, t1, t2, log_theta, bp, C);
    slow_kernel<<<768, 256, 0, stream>>>(X1, X2, log_l, log_theta, bp, t1, t2, C);
}

// Round 19
// 98.793 us; speedup vs baseline: 1.2382x; 1.0065x over previous
//
#include <hip/hip_runtime.h>
#include <stdint.h>

typedef float f32x4 __attribute__((ext_vector_type(4)));
typedef int   i32x4 __attribute__((ext_vector_type(4)));
typedef __bf16 bf16x8 __attribute__((ext_vector_type(8)));

#define NN 8192
#define DDIM 128

// ---- stash layout inside d_out (bytes) ----
// Row = 512B: 4 chunks x [h(32 cols)=64B | l(32 cols)=64B], 16B units
// XOR-swizzled WITHIN each 8-unit chunk by (row&7).
// A'(8192x512B) = C rows 0..127 ; B' = C rows 128..255
// norms n1[8192],n2[8192] f32 = last 64KB = C rows 8190..8191
#define APRIME_OFF 0u
#define BPRIME_OFF (8192u*512u)
#define NORM_OFF   (268435456u - 65536u)

__device__ __forceinline__ uint32_t pk2(__bf16 a, __bf16 b) {
    return (uint32_t)__builtin_bit_cast(unsigned short, a)
         | ((uint32_t)__builtin_bit_cast(unsigned short, b) << 16);
}

__device__ __forceinline__ void gload_lds16(const void* g, void* l) {
    __builtin_amdgcn_global_load_lds(
        (const __attribute__((address_space(1))) uint32_t*)g,
        (__attribute__((address_space(3))) uint32_t*)l,
        16, 0, 0);
}

// ---------------- launch 1: prep — split each row ONCE ----------------
// 1024 blocks x 16 rows (4 rows per wave); per-row math identical to R13-R15
// (bit-identical stash + norms), just fewer launch-bound blocks.
__global__ __launch_bounds__(256) void prep_kernel(
    const float* __restrict__ X1, const float* __restrict__ X2,
    const float* __restrict__ log_l, char* __restrict__ outbuf)
{
    int t = threadIdx.x, wave = t >> 6, lane = t & 63;
    int c0 = lane * 2;
    #pragma unroll
    for (int i = 0; i < 4; ++i) {
        int row = blockIdx.x * 16 + wave * 4 + i;      // 0..16383
        const float* X; uint32_t base; float* nrm;
        if (row < NN) {
            X = X1 + (size_t)row * DDIM;
            base = APRIME_OFF + (uint32_t)row * 512u;
            nrm = (float*)(outbuf + NORM_OFF) + row;
        } else {
            int r2 = row - NN;
            X = X2 + (size_t)r2 * DDIM;
            base = BPRIME_OFF + (uint32_t)r2 * 512u;
            nrm = (float*)(outbuf + NORM_OFF) + NN + r2;
        }
        float2 x = *(const float2*)(X + c0);
        float a0 = x.x * __expf(-log_l[c0]);
        float a1 = x.y * __expf(-log_l[c0 + 1]);
        float ss = a0 * a0 + a1 * a1;
        #pragma unroll
        for (int o = 32; o; o >>= 1) ss += __shfl_down(ss, o);
        if (lane == 0) *nrm = ss;
        __bf16 h0 = (__bf16)a0, h1 = (__bf16)a1;
        __bf16 l0 = (__bf16)(a0 - (float)h0), l1 = (__bf16)(a1 - (float)h1);
        int m = lane >> 2;
        int c = m >> 2;
        int sh = m & 3;
        int sl = 4 | sh;
        int rs = row & 7;
        uint32_t offh = base + (uint32_t)c * 128u + (uint32_t)((sh ^ rs) * 16) + (uint32_t)(lane & 3) * 4u;
        uint32_t offl = base + (uint32_t)c * 128u + (uint32_t)((sl ^ rs) * 16) + (uint32_t)(lane & 3) * 4u;
        *(uint32_t*)(outbuf + offh) = pk2(h0, h1);
        *(uint32_t*)(outbuf + offl) = pk2(l0, l1);
    }
}

// ---------------- launch 2: fast — stash GEMM (R15 structure, NT stores) ----------------
// Single-buffered 32 KB staging, 2 barriers/chunk, 3 blocks/CU (best measured).
// NT stores keep the C write stream out of L2 so the stash stays resident.
__global__ __launch_bounds__(256, 3) void fast_kernel(
    const char* __restrict__ stash,
    const int* __restrict__ task1, const int* __restrict__ task2,
    const float* __restrict__ log_theta_l, const float* __restrict__ bparam,
    float* __restrict__ C)
{
    __shared__ __align__(16) char smem[32768];
    const int t = threadIdx.x;
    const int lane = t & 63, wv = t >> 6;
    const int lr = lane & 15, lg = lane >> 4;
    const float* n1g = (const float*)(stash + NORM_OFF);
    const float* n2g = n1g + NN;
    float logt = log_theta_l[0];
    float bb = bparam[0];
    float lam = fminf(fmaxf(2.f / (1.f + __expf(bb)) - 1.f, 0.f), 1.f);
    int wg = blockIdx.x;

    if (wg < 3840) {
        // ================= full 128x128 tile, tm 2..61 =================
        const int wr = wv >> 1, wc = wv & 1;
        int swz = (wg & 7) * 480 + (wg >> 3);     // bijective XCD chunking
        int tm = 2 + (swz >> 6);
        int tn = swz & 63;
        const char* Abase = stash + APRIME_OFF + (size_t)tm * 128 * 512;
        const char* Bbase = stash + BPRIME_OFF + (size_t)tn * 128 * 512;

        f32x4 acc[4][4];
        #pragma unroll
        for (int i = 0; i < 4; ++i)
            #pragma unroll
            for (int j = 0; j < 4; ++j) acc[i][j] = (f32x4){0.f, 0.f, 0.f, 0.f};

        #define STAGE_F(c) do {                                                       \
            _Pragma("unroll")                                                         \
            for (int i = 0; i < 4; ++i) {                                             \
                int l = t + i * 256;                                                  \
                gload_lds16(Abase + (size_t)(l >> 3) * 512 + (c) * 128 + (l & 7) * 16,\
                            smem + l * 16);                                           \
                gload_lds16(Bbase + (size_t)(l >> 3) * 512 + (c) * 128 + (l & 7) * 16,\
                            smem + 16384 + l * 16);                                   \
            }                                                                         \
        } while (0)

        #define FRAGMM_F() do {                                                       \
            bf16x8 ah[4], bh[4], xf[4];                                               \
            _Pragma("unroll")                                                         \
            for (int mi = 0; mi < 4; ++mi) {                                          \
                int row = wr * 64 + mi * 16 + lr;                                     \
                ah[mi] = *(const bf16x8*)(smem + row * 128 + ((lg ^ (row & 7)) * 16));\
            }                                                                         \
            _Pragma("unroll")                                                         \
            for (int ni = 0; ni < 4; ++ni) {                                          \
                int row = wc * 64 + ni * 16 + lr;                                     \
                bh[ni] = *(const bf16x8*)(smem + 16384 + row * 128                    \
                          + ((lg ^ (row & 7)) * 16));                                 \
            }                                                                         \
            _Pragma("unroll")                                                         \
            for (int mi = 0; mi < 4; ++mi)                                            \
                _Pragma("unroll")                                                     \
                for (int ni = 0; ni < 4; ++ni)                                        \
                    acc[mi][ni] = __builtin_amdgcn_mfma_f32_16x16x32_bf16(            \
                        bh[ni], ah[mi], acc[mi][ni], 0, 0, 0);                        \
            _Pragma("unroll")                                                         \
            for (int mi = 0; mi < 4; ++mi) {                                          \
                int row = wr * 64 + mi * 16 + lr;                                     \
                xf[mi] = *(const bf16x8*)(smem + row * 128                            \
                          + (((4 | lg) ^ (row & 7)) * 16));                           \
            }                                                                         \
            _Pragma("unroll")                                                         \
            for (int mi = 0; mi < 4; ++mi)                                            \
                _Pragma("unroll")                                                     \
                for (int ni = 0; ni < 4; ++ni)                                        \
                    acc[mi][ni] = __builtin_amdgcn_mfma_f32_16x16x32_bf16(            \
                        bh[ni], xf[mi], acc[mi][ni], 0, 0, 0);                        \
            _Pragma("unroll")                                                         \
            for (int ni = 0; ni < 4; ++ni) {                                          \
                int row = wc * 64 + ni * 16 + lr;                                     \
                xf[ni] = *(const bf16x8*)(smem + 16384 + row * 128                    \
                          + (((4 | lg) ^ (row & 7)) * 16));                           \
            }                                                                         \
            _Pragma("unroll")                                                         \
            for (int mi = 0; mi < 4; ++mi)                                            \
                _Pragma("unroll")                                                     \
                for (int ni = 0; ni < 4; ++ni)                                        \
                    acc[mi][ni] = __builtin_amdgcn_mfma_f32_16x16x32_bf16(            \
                        xf[ni], ah[mi], acc[mi][ni], 0, 0, 0);                        \
        } while (0)

        STAGE_F(0);
        __syncthreads();           // staging complete (drains vmcnt)
        FRAGMM_F();
        #pragma unroll
        for (int c = 1; c < 4; ++c) {
            __syncthreads();       // prior reads done before overwrite
            STAGE_F(c);
            __syncthreads();       // staging complete
            FRAGMM_F();
        }

        int rbase = tm * 128, cbase = tn * 128;
        #pragma unroll
        for (int mi = 0; mi < 4; ++mi) {
            int rowl = wr * 64 + mi * 16 + lr;
            float n1v = n1g[rbase + rowl];
            int t1v = task1[rbase + rowl];
            #pragma unroll
            for (int ni = 0; ni < 4; ++ni) {
                int coll = wc * 64 + ni * 16 + lg * 4;
                f32x4 n2v = *(const f32x4*)(n2g + cbase + coll);
                i32x4 t2v = *(const i32x4*)(task2 + cbase + coll);
                f32x4 kv;
                #pragma unroll
                for (int rix = 0; rix < 4; ++rix) {
                    float s = fmaxf(n1v + n2v[rix] - 2.f * acc[mi][ni][rix], 0.f);
                    float k = __expf(fmaf(-0.5f, s, logt));
                    kv[rix] = (t1v != t2v[rix]) ? k * lam : k;
                }
                __builtin_nontemporal_store(kv,
                    (f32x4*)(C + (size_t)(rbase + rowl) * NN + cbase + coll));
            }
        }
        #undef STAGE_F
        #undef FRAGMM_F
    } else {
        // ================= quarter 64x64 tiles, tm = 62 (tail fill) =================
        int wq = wg - 3840;            // 0..255
        int tn = wq >> 2;
        int q = wq & 3;
        int arow0 = 62 * 128 + (q >> 1) * 64;
        int brow0 = tn * 128 + (q & 1) * 64;
        const int wr = wv >> 1, wc = wv & 1;   // 2x2 waves of 32x32
        const char* Abase = stash + APRIME_OFF + (size_t)arow0 * 512;
        const char* Bbase = stash + BPRIME_OFF + (size_t)brow0 * 512;

        f32x4 acc[2][2];
        #pragma unroll
        for (int i = 0; i < 2; ++i)
            #pragma unroll
            for (int j = 0; j < 2; ++j) acc[i][j] = (f32x4){0.f, 0.f, 0.f, 0.f};

        #define STAGE_Q(c) do {                                                       \
            _Pragma("unroll")                                                         \
            for (int i = 0; i < 2; ++i) {                                             \
                int l = t + i * 256;                                                  \
                gload_lds16(Abase + (size_t)(l >> 3) * 512 + (c) * 128 + (l & 7) * 16,\
                            smem + l * 16);                                           \
                gload_lds16(Bbase + (size_t)(l >> 3) * 512 + (c) * 128 + (l & 7) * 16,\
                            smem + 8192 + l * 16);                                    \
            }                                                                         \
        } while (0)

        #define FRAGMM_Q() do {                                                       \
            bf16x8 ah[2], bh[2], xf[2];                                               \
            _Pragma("unroll")                                                         \
            for (int mi = 0; mi < 2; ++mi) {                                          \
                int row = wr * 32 + mi * 16 + lr;                                     \
                ah[mi] = *(const bf16x8*)(smem + row * 128 + ((lg ^ (row & 7)) * 16));\
            }                                                                         \
            _Pragma("unroll")                                                         \
            for (int ni = 0; ni < 2; ++ni) {                                          \
                int row = wc * 32 + ni * 16 + lr;                                     \
                bh[ni] = *(const bf16x8*)(smem + 8192 + row * 128                     \
                          + ((lg ^ (row & 7)) * 16));                                 \
            }                                                                         \
            _Pragma("unroll")                                                         \
            for (int mi = 0; mi < 2; ++mi)                                            \
                _Pragma("unroll")                                                     \
                for (int ni = 0; ni < 2; ++ni)                                        \
                    acc[mi][ni] = __builtin_amdgcn_mfma_f32_16x16x32_bf16(            \
                        bh[ni], ah[mi], acc[mi][ni], 0, 0, 0);                        \
            _Pragma("unroll")                                                         \
            for (int mi = 0; mi < 2; ++mi) {                                          \
                int row = wr * 32 + mi * 16 + lr;                                     \
                xf[mi] = *(const bf16x8*)(smem + row * 128                            \
                          + (((4 | lg) ^ (row & 7)) * 16));                           \
            }                                                                         \
            _Pragma("unroll")                                                         \
            for (int mi = 0; mi < 2; ++mi)                                            \
                _Pragma("unroll")                                                     \
                for (int ni = 0; ni < 2; ++ni)                                        \
                    acc[mi][ni] = __builtin_amdgcn_mfma_f32_16x16x32_bf16(            \
                        bh[ni], xf[mi], acc[mi][ni], 0, 0, 0);                        \
            _Pragma("unroll")                                                         \
            for (int ni = 0; ni < 2; ++ni) {                                          \
                int row = wc * 32 + ni * 16 + lr;                                     \
                xf[ni] = *(const bf16x8*)(smem + 8192 + row * 128                     \
                          + (((4 | lg) ^ (row & 7)) * 16));                           \
            }                                                                         \
            _Pragma("unroll")                                                         \
            for (int mi = 0; mi < 2; ++mi)                                            \
                _Pragma("unroll")                                                     \
                for (int ni = 0; ni < 2; ++ni)                                        \
                    acc[mi][ni] = __builtin_amdgcn_mfma_f32_16x16x32_bf16(            \
                        xf[ni], ah[mi], acc[mi][ni], 0, 0, 0);                        \
        } while (0)

        STAGE_Q(0);
        __syncthreads();
        FRAGMM_Q();
        #pragma unroll
        for (int c = 1; c < 4; ++c) {
            __syncthreads();
            STAGE_Q(c);
            __syncthreads();
            FRAGMM_Q();
        }

        #pragma unroll
        for (int mi = 0; mi < 2; ++mi) {
            int rowl = wr * 32 + mi * 16 + lr;
            float n1v = n1g[arow0 + rowl];
            int t1v = task1[arow0 + rowl];
            #pragma unroll
            for (int ni = 0; ni < 2; ++ni) {
                int coll = wc * 32 + ni * 16 + lg * 4;
                f32x4 n2v = *(const f32x4*)(n2g + brow0 + coll);
                i32x4 t2v = *(const i32x4*)(task2 + brow0 + coll);
                f32x4 kv;
                #pragma unroll
                for (int rix = 0; rix < 4; ++rix) {
                    float s = fmaxf(n1v + n2v[rix] - 2.f * acc[mi][ni][rix], 0.f);
                    float k = __expf(fmaf(-0.5f, s, logt));
                    kv[rix] = (t1v != t2v[rix]) ? k * lam : k;
                }
                __builtin_nontemporal_store(kv,
                    (f32x4*)(C + (size_t)(arow0 + rowl) * NN + brow0 + coll));
            }
        }
        #undef STAGE_Q
        #undef FRAGMM_Q
    }
}

// ---------------- launch 3: slow — R7 pattern at 64x64 quarters, tm in {0,1,63} (R15 verbatim) ----------------
#define RSTRIDE 80
#define SQ_AH 0
#define SQ_AL 5120
#define SQ_BH 10240
#define SQ_BL 15360
#define SQ_ILS 20480
#define SQ_N1  20992
#define SQ_N2  21504
#define SQ_TOT 22016

__device__ __forceinline__ void split4(f32x4 x, uint2& hi, uint2& lo) {
    __bf16 h0 = (__bf16)x[0], h1 = (__bf16)x[1], h2 = (__bf16)x[2], h3 = (__bf16)x[3];
    hi.x = pk2(h0, h1); hi.y = pk2(h2, h3);
    __bf16 l0 = (__bf16)(x[0] - (float)h0);
    __bf16 l1 = (__bf16)(x[1] - (float)h1);
    __bf16 l2 = (__bf16)(x[2] - (float)h2);
    __bf16 l3 = (__bf16)(x[3] - (float)h3);
    lo.x = pk2(l0, l1); lo.y = pk2(l2, l3);
}

__device__ __forceinline__ void lds_barrier() {
    asm volatile("s_waitcnt lgkmcnt(0)" ::: "memory");
    __builtin_amdgcn_sched_barrier(0);
    __builtin_amdgcn_s_barrier();
    __builtin_amdgcn_sched_barrier(0);
}

__global__ __launch_bounds__(256, 3) void slow_kernel(
    const float* __restrict__ X1, const float* __restrict__ X2,
    const float* __restrict__ log_l,
    const float* __restrict__ log_theta_l, const float* __restrict__ bparam,
    const int* __restrict__ task1, const int* __restrict__ task2,
    float* __restrict__ C)
{
    __shared__ __align__(16) char smem[SQ_TOT];
    float* const ils = (float*)(smem + SQ_ILS);
    float* const n1s = (float*)(smem + SQ_N1);
    float* const n2s = (float*)(smem + SQ_N2);

    const int t = threadIdx.x;
    const int lane = t & 63;
    const int wv = t >> 6;
    const int wr = wv >> 1, wc = wv & 1;   // 2x2 waves of 32x32
    const int lr = lane & 15, lg = lane >> 4;
    const int kq = t & 7;
    const int rg = t >> 3;                 // 0..31

    int wg = blockIdx.x;                   // 0..767
    int ti = wg >> 2;                      // 0..191
    int tsel = ti >> 6;
    int tm = (tsel == 2) ? 63 : tsel;
    int tn = ti & 63;
    int q = wg & 3;
    int row0 = tm * 128 + (q >> 1) * 64;
    int col0 = tn * 128 + (q & 1) * 64;

    const float* Ag = X1 + (size_t)row0 * DDIM;
    const float* Bg = X2 + (size_t)col0 * DDIM;

    if (t < 128) ils[t] = __expf(-log_l[t]);

    f32x4 aV[2], bV[2];
    #pragma unroll
    for (int e = 0; e < 2; ++e) {
        aV[e] = *(const f32x4*)(Ag + (size_t)(e * 32 + rg) * DDIM + kq * 4);
        bV[e] = *(const f32x4*)(Bg + (size_t)(e * 32 + rg) * DDIM + kq * 4);
    }
    __syncthreads();

    float nA[2] = {0.f, 0.f};
    float nB[2] = {0.f, 0.f};
    f32x4 acc[2][2];
    #pragma unroll
    for (int i = 0; i < 2; ++i)
        #pragma unroll
        for (int j = 0; j < 2; ++j) acc[i][j] = (f32x4){0.f, 0.f, 0.f, 0.f};

    for (int c = 0; c < 4; ++c) {
        {
            f32x4 il4 = *(const f32x4*)(ils + c * 32 + kq * 4);
            #pragma unroll
            for (int e = 0; e < 2; ++e) {
                int rr = e * 32 + rg;
                f32x4 xa = aV[e] * il4;
                f32x4 xb = bV[e] * il4;
                nA[e] += xa[0]*xa[0] + xa[1]*xa[1] + xa[2]*xa[2] + xa[3]*xa[3];
                nB[e] += xb[0]*xb[0] + xb[1]*xb[1] + xb[2]*xb[2] + xb[3]*xb[3];
                uint2 hA, lA, hB, lB;
                split4(xa, hA, lA);
                split4(xb, hB, lB);
                int boff = rr * RSTRIDE + kq * 8;
                *(uint2*)(smem + SQ_AH + boff) = hA;
                *(uint2*)(smem + SQ_AL + boff) = lA;
                *(uint2*)(smem + SQ_BH + boff) = hB;
                *(uint2*)(smem + SQ_BL + boff) = lB;
            }
        }
        if (c < 3) {
            #pragma unroll
            for (int e = 0; e < 2; ++e) {
                aV[e] = *(const f32x4*)(Ag + (size_t)(e * 32 + rg) * DDIM + (c + 1) * 32 + kq * 4);
                bV[e] = *(const f32x4*)(Bg + (size_t)(e * 32 + rg) * DDIM + (c + 1) * 32 + kq * 4);
            }
        }
        lds_barrier();
        {
            bf16x8 ah[2], bh[2], xf[2];
            #pragma unroll
            for (int mi = 0; mi < 2; ++mi) {
                int off = (wr * 32 + mi * 16 + lr) * RSTRIDE + lg * 16;
                ah[mi] = *(const bf16x8*)(smem + SQ_AH + off);
            }
            #pragma unroll
            for (int ni = 0; ni < 2; ++ni) {
                int off = (wc * 32 + ni * 16 + lr) * RSTRIDE + lg * 16;
                bh[ni] = *(const bf16x8*)(smem + SQ_BH + off);
            }
            #pragma unroll
            for (int mi = 0; mi < 2; ++mi)
                #pragma unroll
                for (int ni = 0; ni < 2; ++ni)
                    acc[mi][ni] = __builtin_amdgcn_mfma_f32_16x16x32_bf16(bh[ni], ah[mi], acc[mi][ni], 0, 0, 0);
            #pragma unroll
            for (int mi = 0; mi < 2; ++mi) {
                int off = (wr * 32 + mi * 16 + lr) * RSTRIDE + lg * 16;
                xf[mi] = *(const bf16x8*)(smem + SQ_AL + off);
            }
            #pragma unroll
            for (int mi = 0; mi < 2; ++mi)
                #pragma unroll
                for (int ni = 0; ni < 2; ++ni)
                    acc[mi][ni] = __builtin_amdgcn_mfma_f32_16x16x32_bf16(bh[ni], xf[mi], acc[mi][ni], 0, 0, 0);
            #pragma unroll
            for (int ni = 0; ni < 2; ++ni) {
                int off = (wc * 32 + ni * 16 + lr) * RSTRIDE + lg * 16;
                xf[ni] = *(const bf16x8*)(smem + SQ_BL + off);
            }
            #pragma unroll
            for (int mi = 0; mi < 2; ++mi)
                #pragma unroll
                for (int ni = 0; ni < 2; ++ni)
                    acc[mi][ni] = __builtin_amdgcn_mfma_f32_16x16x32_bf16(xf[ni], ah[mi], acc[mi][ni], 0, 0, 0);
        }
        lds_barrier();
    }

    #pragma unroll
    for (int e = 0; e < 2; ++e) {
        #pragma unroll
        for (int off = 1; off < 8; off <<= 1) {
            nA[e] += __shfl_xor(nA[e], off);
            nB[e] += __shfl_xor(nB[e], off);
        }
    }
    if (kq == 0) {
        #pragma unroll
        for (int e = 0; e < 2; ++e) {
            n1s[e * 32 + rg] = nA[e];
            n2s[e * 32 + rg] = nB[e];
        }
    }
    __syncthreads();

    float logt = log_theta_l[0];
    float bb = bparam[0];
    float lam = fminf(fmaxf(2.f / (1.f + __expf(bb)) - 1.f, 0.f), 1.f);

    #pragma unroll
    for (int mi = 0; mi < 2; ++mi) {
        int rowl = wr * 32 + mi * 16 + lr;
        float n1v = n1s[rowl];
        int t1v = task1[row0 + rowl];
        #pragma unroll
        for (int ni = 0; ni < 2; ++ni) {
            int coll = wc * 32 + ni * 16 + lg * 4;
            f32x4 n2v = *(const f32x4*)(n2s + coll);
            i32x4 t2v = *(const i32x4*)(task2 + col0 + coll);
            f32x4 kv;
            #pragma unroll
            for (int rix = 0; rix < 4; ++rix) {
                float s = fmaxf(n1v + n2v[rix] - 2.f * acc[mi][ni][rix], 0.f);
                float k = __expf(fmaf(-0.5f, s, logt));
                kv[rix] = (t1v != t2v[rix]) ? k * lam : k;
            }
            *(f32x4*)(C + (size_t)(row0 + rowl) * NN + col0 + coll) = kv;
        }
    }
}

extern "C" void kernel_launch(void* const* d_in, const int* in_sizes, int n_in,
                              void* d_out, int out_size, void* d_ws, size_t ws_size,
                              hipStream_t stream)
{
    const float* X1 = (const float*)d_in[0];
    const float* X2 = (const float*)d_in[1];
    const float* log_l = (const float*)d_in[2];
    const float* log_theta = (const float*)d_in[3];
    const float* bp = (const float*)d_in[4];
    const int* t1 = (const int*)d_in[5];
    const int* t2 = (const int*)d_in[6];
    float* C = (float*)d_out;
    (void)d_ws; (void)ws_size; (void)in_sizes; (void)n_in; (void)out_size;

    prep_kernel<<<1024, 256, 0, stream>>>(X1, X2, log_l, (char*)d_out);
    fast_kernel<<<4096, 256, 0, stream>>>((const char*)d_out, t1, t2, log_theta, bp, C);
    slow_kernel<<<768, 256, 0, stream>>>(X1, X2, log_l, log_theta, bp, t1, t2, C);
}

// Round 20
// 97.371 us; speedup vs baseline: 1.2563x; 1.0146x over previous
//
#include <hip/hip_runtime.h>
#include <stdint.h>

typedef float f32x4 __attribute__((ext_vector_type(4)));
typedef int   i32x4 __attribute__((ext_vector_type(4)));
typedef __bf16 bf16x8 __attribute__((ext_vector_type(8)));

#define NN 8192
#define DDIM 128

// ---- stash layout inside d_out (bytes) ----
// Row = 512B: 4 chunks x [h(32 cols)=64B | l(32 cols)=64B], 16B units
// XOR-swizzled WITHIN each 8-unit chunk by (row&7).
// A'(8192x512B) = C rows 0..127 ; B' = C rows 128..255
// norms n1[8192],n2[8192] f32 = last 64KB = C rows 8190..8191
#define APRIME_OFF 0u
#define BPRIME_OFF (8192u*512u)
#define NORM_OFF   (268435456u - 65536u)

__device__ __forceinline__ uint32_t pk2(__bf16 a, __bf16 b) {
    return (uint32_t)__builtin_bit_cast(unsigned short, a)
         | ((uint32_t)__builtin_bit_cast(unsigned short, b) << 16);
}

__device__ __forceinline__ void gload_lds16(const void* g, void* l) {
    __builtin_amdgcn_global_load_lds(
        (const __attribute__((address_space(1))) uint32_t*)g,
        (__attribute__((address_space(3))) uint32_t*)l,
        16, 0, 0);
}

// T4 counted-vmcnt barrier: wait until <=N of THIS wave's vmem ops remain,
// then block-barrier. sched_barrier(0) fences hoisting (rule #18).
#define BAR_VMCNT(N) do {                                          \
    asm volatile("s_waitcnt vmcnt(" #N ")" ::: "memory");          \
    __builtin_amdgcn_sched_barrier(0);                             \
    __builtin_amdgcn_s_barrier();                                  \
    __builtin_amdgcn_sched_barrier(0);                             \
} while (0)

// LDS-read-completion barrier (before overwriting a buffer): lgkm only.
#define BAR_LGKM() do {                                            \
    asm volatile("s_waitcnt lgkmcnt(0)" ::: "memory");             \
    __builtin_amdgcn_sched_barrier(0);                             \
    __builtin_amdgcn_s_barrier();                                  \
    __builtin_amdgcn_sched_barrier(0);                             \
} while (0)

// ---------------- launch 1: prep — split each row ONCE (R18/R19 verbatim) ----------------
__global__ __launch_bounds__(256) void prep_kernel(
    const float* __restrict__ X1, const float* __restrict__ X2,
    const float* __restrict__ log_l, char* __restrict__ outbuf)
{
    int t = threadIdx.x, wave = t >> 6, lane = t & 63;
    int c0 = lane * 2;
    #pragma unroll
    for (int i = 0; i < 4; ++i) {
        int row = blockIdx.x * 16 + wave * 4 + i;      // 0..16383
        const float* X; uint32_t base; float* nrm;
        if (row < NN) {
            X = X1 + (size_t)row * DDIM;
            base = APRIME_OFF + (uint32_t)row * 512u;
            nrm = (float*)(outbuf + NORM_OFF) + row;
        } else {
            int r2 = row - NN;
            X = X2 + (size_t)r2 * DDIM;
            base = BPRIME_OFF + (uint32_t)r2 * 512u;
            nrm = (float*)(outbuf + NORM_OFF) + NN + r2;
        }
        float2 x = *(const float2*)(X + c0);
        float a0 = x.x * __expf(-log_l[c0]);
        float a1 = x.y * __expf(-log_l[c0 + 1]);
        float ss = a0 * a0 + a1 * a1;
        #pragma unroll
        for (int o = 32; o; o >>= 1) ss += __shfl_down(ss, o);
        if (lane == 0) *nrm = ss;
        __bf16 h0 = (__bf16)a0, h1 = (__bf16)a1;
        __bf16 l0 = (__bf16)(a0 - (float)h0), l1 = (__bf16)(a1 - (float)h1);
        int m = lane >> 2;
        int c = m >> 2;
        int sh = m & 3;
        int sl = 4 | sh;
        int rs = row & 7;
        uint32_t offh = base + (uint32_t)c * 128u + (uint32_t)((sh ^ rs) * 16) + (uint32_t)(lane & 3) * 4u;
        uint32_t offl = base + (uint32_t)c * 128u + (uint32_t)((sl ^ rs) * 16) + (uint32_t)(lane & 3) * 4u;
        *(uint32_t*)(outbuf + offh) = pk2(h0, h1);
        *(uint32_t*)(outbuf + offl) = pk2(l0, l1);
    }
}

// ---------------- launch 2: fast — stash GEMM, dbuf + COUNTED vmcnt (T4) ----------------
// Chunks {0,2}->buf0, {1,3}->buf1. Stage of chunk c+1 stays in flight across
// FRAGMM(c); vmcnt(8) retires exactly the older chunk's 8 loads (FIFO).
// Buffer overwrite always one lgkm-barrier after its last reader.
__global__ __launch_bounds__(256, 2) void fast_kernel(
    const char* __restrict__ stash,
    const int* __restrict__ task1, const int* __restrict__ task2,
    const float* __restrict__ log_theta_l, const float* __restrict__ bparam,
    float* __restrict__ C)
{
    __shared__ __align__(16) char smem[65536];   // 2 x {A 16K | B 16K}
    const int t = threadIdx.x;
    const int lane = t & 63, wv = t >> 6;
    const int lr = lane & 15, lg = lane >> 4;
    const float* n1g = (const float*)(stash + NORM_OFF);
    const float* n2g = n1g + NN;
    float logt = log_theta_l[0];
    float bb = bparam[0];
    float lam = fminf(fmaxf(2.f / (1.f + __expf(bb)) - 1.f, 0.f), 1.f);
    int wg = blockIdx.x;

    if (wg < 3840) {
        // ================= full 128x128 tile, tm 2..61 =================
        const int wr = wv >> 1, wc = wv & 1;
        int swz = (wg & 7) * 480 + (wg >> 3);     // bijective XCD chunking
        int tm = 2 + (swz >> 6);
        int tn = swz & 63;
        const char* Abase = stash + APRIME_OFF + (size_t)tm * 128 * 512;
        const char* Bbase = stash + BPRIME_OFF + (size_t)tn * 128 * 512;

        f32x4 acc[4][4];
        #pragma unroll
        for (int i = 0; i < 4; ++i)
            #pragma unroll
            for (int j = 0; j < 4; ++j) acc[i][j] = (f32x4){0.f, 0.f, 0.f, 0.f};

        #define STAGE_F(c, buf) do {                                              \
            _Pragma("unroll")                                                     \
            for (int i = 0; i < 4; ++i) {                                         \
                int l = t + i * 256;                                              \
                gload_lds16(Abase + (size_t)(l >> 3) * 512 + (c) * 128 + (l & 7) * 16,\
                            smem + (buf) * 32768 + l * 16);                       \
                gload_lds16(Bbase + (size_t)(l >> 3) * 512 + (c) * 128 + (l & 7) * 16,\
                            smem + (buf) * 32768 + 16384 + l * 16);               \
            }                                                                     \
        } while (0)

        #define FRAGMM_F(buf) do {                                                \
            const char* tb_ = smem + (buf) * 32768;                               \
            bf16x8 ah[4], bh[4], xf[4];                                           \
            _Pragma("unroll")                                                     \
            for (int mi = 0; mi < 4; ++mi) {                                      \
                int row = wr * 64 + mi * 16 + lr;                                 \
                ah[mi] = *(const bf16x8*)(tb_ + row * 128 + ((lg ^ (row & 7)) * 16));\
            }                                                                     \
            _Pragma("unroll")                                                     \
            for (int ni = 0; ni < 4; ++ni) {                                      \
                int row = wc * 64 + ni * 16 + lr;                                 \
                bh[ni] = *(const bf16x8*)(tb_ + 16384 + row * 128                 \
                          + ((lg ^ (row & 7)) * 16));                             \
            }                                                                     \
            _Pragma("unroll")                                                     \
            for (int mi = 0; mi < 4; ++mi)                                        \
                _Pragma("unroll")                                                 \
                for (int ni = 0; ni < 4; ++ni)                                    \
                    acc[mi][ni] = __builtin_amdgcn_mfma_f32_16x16x32_bf16(        \
                        bh[ni], ah[mi], acc[mi][ni], 0, 0, 0);                    \
            _Pragma("unroll")                                                     \
            for (int mi = 0; mi < 4; ++mi) {                                      \
                int row = wr * 64 + mi * 16 + lr;                                 \
                xf[mi] = *(const bf16x8*)(tb_ + row * 128                         \
                          + (((4 | lg) ^ (row & 7)) * 16));                       \
            }                                                                     \
            _Pragma("unroll")                                                     \
            for (int mi = 0; mi < 4; ++mi)                                        \
                _Pragma("unroll")                                                 \
                for (int ni = 0; ni < 4; ++ni)                                    \
                    acc[mi][ni] = __builtin_amdgcn_mfma_f32_16x16x32_bf16(        \
                        bh[ni], xf[mi], acc[mi][ni], 0, 0, 0);                    \
            _Pragma("unroll")                                                     \
            for (int ni = 0; ni < 4; ++ni) {                                      \
                int row = wc * 64 + ni * 16 + lr;                                 \
                xf[ni] = *(const bf16x8*)(tb_ + 16384 + row * 128                 \
                          + (((4 | lg) ^ (row & 7)) * 16));                       \
            }                                                                     \
            _Pragma("unroll")                                                     \
            for (int mi = 0; mi < 4; ++mi)                                        \
                _Pragma("unroll")                                                 \
                for (int ni = 0; ni < 4; ++ni)                                    \
                    acc[mi][ni] = __builtin_amdgcn_mfma_f32_16x16x32_bf16(        \
                        xf[ni], ah[mi], acc[mi][ni], 0, 0, 0);                    \
        } while (0)

        // T4 pipeline: 8 loads per STAGE; vmcnt(8) = older chunk landed.
        STAGE_F(0, 0);
        STAGE_F(1, 1);          // 16 in flight
        BAR_VMCNT(8);           // chunk0 landed (all waves)
        FRAGMM_F(0);            // chunk0 from buf0; chunk1 still streaming
        BAR_LGKM();             // buf0 reads done
        STAGE_F(2, 0);          // <=16 in flight
        BAR_VMCNT(8);           // chunk1 landed
        FRAGMM_F(1);            // chunk1 from buf1
        BAR_LGKM();             // buf1 reads done
        STAGE_F(3, 1);          // <=16 in flight
        BAR_VMCNT(8);           // chunk2 landed
        FRAGMM_F(0);            // chunk2 from buf0
        BAR_VMCNT(0);           // chunk3 landed
        FRAGMM_F(1);            // chunk3 from buf1

        int rbase = tm * 128, cbase = tn * 128;
        #pragma unroll
        for (int mi = 0; mi < 4; ++mi) {
            int rowl = wr * 64 + mi * 16 + lr;
            float n1v = n1g[rbase + rowl];
            int t1v = task1[rbase + rowl];
            #pragma unroll
            for (int ni = 0; ni < 4; ++ni) {
                int coll = wc * 64 + ni * 16 + lg * 4;
                f32x4 n2v = *(const f32x4*)(n2g + cbase + coll);
                i32x4 t2v = *(const i32x4*)(task2 + cbase + coll);
                f32x4 kv;
                #pragma unroll
                for (int rix = 0; rix < 4; ++rix) {
                    float s = fmaxf(n1v + n2v[rix] - 2.f * acc[mi][ni][rix], 0.f);
                    float k = __expf(fmaf(-0.5f, s, logt));
                    kv[rix] = (t1v != t2v[rix]) ? k * lam : k;
                }
                __builtin_nontemporal_store(kv,
                    (f32x4*)(C + (size_t)(rbase + rowl) * NN + cbase + coll));
            }
        }
        #undef STAGE_F
        #undef FRAGMM_F
    } else {
        // ================= quarter 64x64 tiles, tm = 62 (tail fill) =================
        int wq = wg - 3840;            // 0..255
        int tn = wq >> 2;
        int q = wq & 3;
        int arow0 = 62 * 128 + (q >> 1) * 64;
        int brow0 = tn * 128 + (q & 1) * 64;
        const int wr = wv >> 1, wc = wv & 1;   // 2x2 waves of 32x32
        const char* Abase = stash + APRIME_OFF + (size_t)arow0 * 512;
        const char* Bbase = stash + BPRIME_OFF + (size_t)brow0 * 512;

        f32x4 acc[2][2];
        #pragma unroll
        for (int i = 0; i < 2; ++i)
            #pragma unroll
            for (int j = 0; j < 2; ++j) acc[i][j] = (f32x4){0.f, 0.f, 0.f, 0.f};

        #define STAGE_Q(c, buf) do {                                              \
            _Pragma("unroll")                                                     \
            for (int i = 0; i < 2; ++i) {                                         \
                int l = t + i * 256;                                              \
                gload_lds16(Abase + (size_t)(l >> 3) * 512 + (c) * 128 + (l & 7) * 16,\
                            smem + (buf) * 32768 + l * 16);                       \
                gload_lds16(Bbase + (size_t)(l >> 3) * 512 + (c) * 128 + (l & 7) * 16,\
                            smem + (buf) * 32768 + 8192 + l * 16);                \
            }                                                                     \
        } while (0)

        #define FRAGMM_Q(buf) do {                                                \
            const char* tb_ = smem + (buf) * 32768;                               \
            bf16x8 ah[2], bh[2], xf[2];                                           \
            _Pragma("unroll")                                                     \
            for (int mi = 0; mi < 2; ++mi) {                                      \
                int row = wr * 32 + mi * 16 + lr;                                 \
                ah[mi] = *(const bf16x8*)(tb_ + row * 128 + ((lg ^ (row & 7)) * 16));\
            }                                                                     \
            _Pragma("unroll")                                                     \
            for (int ni = 0; ni < 2; ++ni) {                                      \
                int row = wc * 32 + ni * 16 + lr;                                 \
                bh[ni] = *(const bf16x8*)(tb_ + 8192 + row * 128                  \
                          + ((lg ^ (row & 7)) * 16));                             \
            }                                                                     \
            _Pragma("unroll")                                                     \
            for (int mi = 0; mi < 2; ++mi)                                        \
                _Pragma("unroll")                                                 \
                for (int ni = 0; ni < 2; ++ni)                                    \
                    acc[mi][ni] = __builtin_amdgcn_mfma_f32_16x16x32_bf16(        \
                        bh[ni], ah[mi], acc[mi][ni], 0, 0, 0);                    \
            _Pragma("unroll")                                                     \
            for (int mi = 0; mi < 2; ++mi) {                                      \
                int row = wr * 32 + mi * 16 + lr;                                 \
                xf[mi] = *(const bf16x8*)(tb_ + row * 128                         \
                          + (((4 | lg) ^ (row & 7)) * 16));                       \
            }                                                                     \
            _Pragma("unroll")                                                     \
            for (int mi = 0; mi < 2; ++mi)                                        \
                _Pragma("unroll")                                                 \
                for (int ni = 0; ni < 2; ++ni)                                    \
                    acc[mi][ni] = __builtin_amdgcn_mfma_f32_16x16x32_bf16(        \
                        bh[ni], xf[mi], acc[mi][ni], 0, 0, 0);                    \
            _Pragma("unroll")                                                     \
            for (int ni = 0; ni < 2; ++ni) {                                      \
                int row = wc * 32 + ni * 16 + lr;                                 \
                xf[ni] = *(const bf16x8*)(tb_ + 8192 + row * 128                  \
                          + (((4 | lg) ^ (row & 7)) * 16));                       \
            }                                                                     \
            _Pragma("unroll")                                                     \
            for (int mi = 0; mi < 2; ++mi)                                        \
                _Pragma("unroll")                                                 \
                for (int ni = 0; ni < 2; ++ni)                                    \
                    acc[mi][ni] = __builtin_amdgcn_mfma_f32_16x16x32_bf16(        \
                        xf[ni], ah[mi], acc[mi][ni], 0, 0, 0);                    \
        } while (0)

        // same T4 pipeline; 4 loads per STAGE -> vmcnt(4)
        STAGE_Q(0, 0);
        STAGE_Q(1, 1);
        BAR_VMCNT(4);
        FRAGMM_Q(0);
        BAR_LGKM();
        STAGE_Q(2, 0);
        BAR_VMCNT(4);
        FRAGMM_Q(1);
        BAR_LGKM();
        STAGE_Q(3, 1);
        BAR_VMCNT(4);
        FRAGMM_Q(0);
        BAR_VMCNT(0);
        FRAGMM_Q(1);

        #pragma unroll
        for (int mi = 0; mi < 2; ++mi) {
            int rowl = wr * 32 + mi * 16 + lr;
            float n1v = n1g[arow0 + rowl];
            int t1v = task1[arow0 + rowl];
            #pragma unroll
            for (int ni = 0; ni < 2; ++ni) {
                int coll = wc * 32 + ni * 16 + lg * 4;
                f32x4 n2v = *(const f32x4*)(n2g + brow0 + coll);
                i32x4 t2v = *(const i32x4*)(task2 + brow0 + coll);
                f32x4 kv;
                #pragma unroll
                for (int rix = 0; rix < 4; ++rix) {
                    float s = fmaxf(n1v + n2v[rix] - 2.f * acc[mi][ni][rix], 0.f);
                    float k = __expf(fmaf(-0.5f, s, logt));
                    kv[rix] = (t1v != t2v[rix]) ? k * lam : k;
                }
                __builtin_nontemporal_store(kv,
                    (f32x4*)(C + (size_t)(arow0 + rowl) * NN + brow0 + coll));
            }
        }
        #undef STAGE_Q
        #undef FRAGMM_Q
    }
}

// ---------------- launch 3: slow — R7 pattern at 64x64 quarters, tm in {0,1,63} (R15 verbatim) ----------------
#define RSTRIDE 80
#define SQ_AH 0
#define SQ_AL 5120
#define SQ_BH 10240
#define SQ_BL 15360
#define SQ_ILS 20480
#define SQ_N1  20992
#define SQ_N2  21504
#define SQ_TOT 22016

__device__ __forceinline__ void split4(f32x4 x, uint2& hi, uint2& lo) {
    __bf16 h0 = (__bf16)x[0], h1 = (__bf16)x[1], h2 = (__bf16)x[2], h3 = (__bf16)x[3];
    hi.x = pk2(h0, h1); hi.y = pk2(h2, h3);
    __bf16 l0 = (__bf16)(x[0] - (float)h0);
    __bf16 l1 = (__bf16)(x[1] - (float)h1);
    __bf16 l2 = (__bf16)(x[2] - (float)h2);
    __bf16 l3 = (__bf16)(x[3] - (float)h3);
    lo.x = pk2(l0, l1); lo.y = pk2(l2, l3);
}

__device__ __forceinline__ void lds_barrier() {
    asm volatile("s_waitcnt lgkmcnt(0)" ::: "memory");
    __builtin_amdgcn_sched_barrier(0);
    __builtin_amdgcn_s_barrier();
    __builtin_amdgcn_sched_barrier(0);
}

__global__ __launch_bounds__(256, 3) void slow_kernel(
    const float* __restrict__ X1, const float* __restrict__ X2,
    const float* __restrict__ log_l,
    const float* __restrict__ log_theta_l, const float* __restrict__ bparam,
    const int* __restrict__ task1, const int* __restrict__ task2,
    float* __restrict__ C)
{
    __shared__ __align__(16) char smem[SQ_TOT];
    float* const ils = (float*)(smem + SQ_ILS);
    float* const n1s = (float*)(smem + SQ_N1);
    float* const n2s = (float*)(smem + SQ_N2);

    const int t = threadIdx.x;
    const int lane = t & 63;
    const int wv = t >> 6;
    const int wr = wv >> 1, wc = wv & 1;   // 2x2 waves of 32x32
    const int lr = lane & 15, lg = lane >> 4;
    const int kq = t & 7;
    const int rg = t >> 3;                 // 0..31

    int wg = blockIdx.x;                   // 0..767
    int ti = wg >> 2;                      // 0..191
    int tsel = ti >> 6;
    int tm = (tsel == 2) ? 63 : tsel;
    int tn = ti & 63;
    int q = wg & 3;
    int row0 = tm * 128 + (q >> 1) * 64;
    int col0 = tn * 128 + (q & 1) * 64;

    const float* Ag = X1 + (size_t)row0 * DDIM;
    const float* Bg = X2 + (size_t)col0 * DDIM;

    if (t < 128) ils[t] = __expf(-log_l[t]);

    f32x4 aV[2], bV[2];
    #pragma unroll
    for (int e = 0; e < 2; ++e) {
        aV[e] = *(const f32x4*)(Ag + (size_t)(e * 32 + rg) * DDIM + kq * 4);
        bV[e] = *(const f32x4*)(Bg + (size_t)(e * 32 + rg) * DDIM + kq * 4);
    }
    __syncthreads();

    float nA[2] = {0.f, 0.f};
    float nB[2] = {0.f, 0.f};
    f32x4 acc[2][2];
    #pragma unroll
    for (int i = 0; i < 2; ++i)
        #pragma unroll
        for (int j = 0; j < 2; ++j) acc[i][j] = (f32x4){0.f, 0.f, 0.f, 0.f};

    for (int c = 0; c < 4; ++c) {
        {
            f32x4 il4 = *(const f32x4*)(ils + c * 32 + kq * 4);
            #pragma unroll
            for (int e = 0; e < 2; ++e) {
                int rr = e * 32 + rg;
                f32x4 xa = aV[e] * il4;
                f32x4 xb = bV[e] * il4;
                nA[e] += xa[0]*xa[0] + xa[1]*xa[1] + xa[2]*xa[2] + xa[3]*xa[3];
                nB[e] += xb[0]*xb[0] + xb[1]*xb[1] + xb[2]*xb[2] + xb[3]*xb[3];
                uint2 hA, lA, hB, lB;
                split4(xa, hA, lA);
                split4(xb, hB, lB);
                int boff = rr * RSTRIDE + kq * 8;
                *(uint2*)(smem + SQ_AH + boff) = hA;
                *(uint2*)(smem + SQ_AL + boff) = lA;
                *(uint2*)(smem + SQ_BH + boff) = hB;
                *(uint2*)(smem + SQ_BL + boff) = lB;
            }
        }
        if (c < 3) {
            #pragma unroll
            for (int e = 0; e < 2; ++e) {
                aV[e] = *(const f32x4*)(Ag + (size_t)(e * 32 + rg) * DDIM + (c + 1) * 32 + kq * 4);
                bV[e] = *(const f32x4*)(Bg + (size_t)(e * 32 + rg) * DDIM + (c + 1) * 32 + kq * 4);
            }
        }
        lds_barrier();
        {
            bf16x8 ah[2], bh[2], xf[2];
            #pragma unroll
            for (int mi = 0; mi < 2; ++mi) {
                int off = (wr * 32 + mi * 16 + lr) * RSTRIDE + lg * 16;
                ah[mi] = *(const bf16x8*)(smem + SQ_AH + off);
            }
            #pragma unroll
            for (int ni = 0; ni < 2; ++ni) {
                int off = (wc * 32 + ni * 16 + lr) * RSTRIDE + lg * 16;
                bh[ni] = *(const bf16x8*)(smem + SQ_BH + off);
            }
            #pragma unroll
            for (int mi = 0; mi < 2; ++mi)
                #pragma unroll
                for (int ni = 0; ni < 2; ++ni)
                    acc[mi][ni] = __builtin_amdgcn_mfma_f32_16x16x32_bf16(bh[ni], ah[mi], acc[mi][ni], 0, 0, 0);
            #pragma unroll
            for (int mi = 0; mi < 2; ++mi) {
                int off = (wr * 32 + mi * 16 + lr) * RSTRIDE + lg * 16;
                xf[mi] = *(const bf16x8*)(smem + SQ_AL + off);
            }
            #pragma unroll
            for (int mi = 0; mi < 2; ++mi)
                #pragma unroll
                for (int ni = 0; ni < 2; ++ni)
                    acc[mi][ni] = __builtin_amdgcn_mfma_f32_16x16x32_bf16(bh[ni], xf[mi], acc[mi][ni], 0, 0, 0);
            #pragma unroll
            for (int ni = 0; ni < 2; ++ni) {
                int off = (wc * 32 + ni * 16 + lr) * RSTRIDE + lg * 16;
                xf[ni] = *(const bf16x8*)(smem + SQ_BL + off);
            }
            #pragma unroll
            for (int mi = 0; mi < 2; ++mi)
                #pragma unroll
                for (int ni = 0; ni < 2; ++ni)
                    acc[mi][ni] = __builtin_amdgcn_mfma_f32_16x16x32_bf16(xf[ni], ah[mi], acc[mi][ni], 0, 0, 0);
        }
        lds_barrier();
    }

    #pragma unroll
    for (int e = 0; e < 2; ++e) {
        #pragma unroll
        for (int off = 1; off < 8; off <<= 1) {
            nA[e] += __shfl_xor(nA[e], off);
            nB[e] += __shfl_xor(nB[e], off);
        }
    }
    if (kq == 0) {
        #pragma unroll
        for (int e = 0; e < 2; ++e) {
            n1s[e * 32 + rg] = nA[e];
            n2s[e * 32 + rg] = nB[e];
        }
    }
    __syncthreads();

    float logt = log_theta_l[0];
    float bb = bparam[0];
    float lam = fminf(fmaxf(2.f / (1.f + __expf(bb)) - 1.f, 0.f), 1.f);

    #pragma unroll
    for (int mi = 0; mi < 2; ++mi) {
        int rowl = wr * 32 + mi * 16 + lr;
        float n1v = n1s[rowl];
        int t1v = task1[row0 + rowl];
        #pragma unroll
        for (int ni = 0; ni < 2; ++ni) {
            int coll = wc * 32 + ni * 16 + lg * 4;
            f32x4 n2v = *(const f32x4*)(n2s + coll);
            i32x4 t2v = *(const i32x4*)(task2 + col0 + coll);
            f32x4 kv;
            #pragma unroll
            for (int rix = 0; rix < 4; ++rix) {
                float s = fmaxf(n1v + n2v[rix] - 2.f * acc[mi][ni][rix], 0.f);
                float k = __expf(fmaf(-0.5f, s, logt));
                kv[rix] = (t1v != t2v[rix]) ? k * lam : k;
            }
            *(f32x4*)(C + (size_t)(row0 + rowl) * NN + col0 + coll) = kv;
        }
    }
}

extern "C" void kernel_launch(void* const* d_in, const int* in_sizes, int n_in,
                              void* d_out, int out_size, void* d_ws, size_t ws_size,
                              hipStream_t stream)
{
    const float* X1 = (const float*)d_in[0];
    const float* X2 = (const float*)d_in[1];
    const float* log_l = (const float*)d_in[2];
    const float* log_theta = (const float*)d_in[3];
    const float* bp = (const float*)d_in[4];
    const int* t1 = (const int*)d_in[5];
    const int* t2 = (const int*)d_in[6];
    float* C = (float*)d_out;
    (void)d_ws; (void)ws_size; (void)in_sizes; (void)n_in; (void)out_size;

    prep_kernel<<<1024, 256, 0, stream>>>(X1, X2, log_l, (char*)d_out);
    fast_kernel<<<4096, 256, 0, stream>>>((const char*)d_out, t1, t2, log_theta, bp, C);
    slow_kernel<<<768, 256, 0, stream>>>(X1, X2, log_l, log_theta, bp, t1, t2, C);
}